// Round 1
// baseline (2992.040 us; speedup 1.0000x reference)
//
#include <hip/hip_runtime.h>
#include <hip/hip_bf16.h>

#define Bsz 256
#define Ssz 512
#define Fsz 64
#define Hsz 128
#define NG  512   // 4*H

typedef unsigned short ushort_t;

// --- kernel 1: inv_denom[s] = 1 / (sum_{b,f} m[b,s,f] + 1e-5) ---
__global__ void denom_kernel(const float* __restrict__ m, float* __restrict__ inv_denom) {
  int s = blockIdx.x;
  int tid = threadIdx.x; // 256 threads, one per batch row
  const float4* mp = (const float4*)(m + ((size_t)tid * Ssz + s) * Fsz);
  float sum = 0.f;
#pragma unroll
  for (int i = 0; i < Fsz / 4; ++i) {
    float4 v = mp[i];
    sum += v.x + v.y + v.z + v.w;
  }
  for (int off = 32; off > 0; off >>= 1) sum += __shfl_xor(sum, off);
  __shared__ float red[4];
  if ((tid & 63) == 0) red[tid >> 6] = sum;
  __syncthreads();
  if (tid == 0) {
    float tot = red[0] + red[1] + red[2] + red[3];
    inv_denom[s] = 1.0f / (tot + 1e-5f);
  }
}

// --- kernel 2: pack [Wih | Whh] (f32, row-major [512][128] each) into bf16
//     layout Wpk[kk][j][p] : k = kk*8+p,  j = gate index.  uint4-addressable. ---
__global__ void pack_kernel(const float* __restrict__ Wih, const float* __restrict__ Whh,
                            ushort_t* __restrict__ Wpk) {
  int g = blockIdx.x * blockDim.x + threadIdx.x;
  if (g >= NG * 32) return;
  int j = g >> 5, kk = g & 31;
  ushort_t* dst = Wpk + ((size_t)(kk * NG + j)) * 8;
#pragma unroll
  for (int p = 0; p < 8; ++p) {
    int k = kk * 8 + p;
    float w = (k < 128) ? Wih[j * 128 + k] : Whh[j * 128 + (k - 128)];
    unsigned int bits = __float_as_uint(w);
    unsigned int r = (bits + 0x7fffu + ((bits >> 16) & 1u)) >> 16;  // RNE bf16
    dst[p] = (ushort_t)r;
  }
}

// --- kernel 3: the recurrence. One block per batch row, 512 threads. ---
__launch_bounds__(512, 1)
__global__ void rits_kernel(
    const float* __restrict__ x, const float* __restrict__ m, const float* __restrict__ t,
    const float* __restrict__ Wdh, const float* __restrict__ bdh,
    const float* __restrict__ Wdm, const float* __restrict__ bdm,
    const float* __restrict__ Wtr, const float* __restrict__ btr,
    const float* __restrict__ Wfr, const float* __restrict__ bfr,
    const float* __restrict__ Wwc, const float* __restrict__ bwc,
    const float* __restrict__ bih, const float* __restrict__ bhh,
    const ushort_t* __restrict__ Wpk, const float* __restrict__ inv_denom,
    float* __restrict__ out_imp, float* __restrict__ out_loss)
{
  const int b = blockIdx.x;
  const int tid = threadIdx.x;

  // LDS staging (~127 KB total -> 1 block/CU)
  __shared__ float sWdh[Hsz][68];    // [h][f], pad 68
  __shared__ float sWtr[Fsz][132];   // [f][h], pad 132
  __shared__ float sWwc[Fsz][132];   // [f][2f], pad 132
  __shared__ float sWfr[Fsz][68];    // [f][f], diag zeroed
  __shared__ float sBias[NG];        // bih + bhh
  __shared__ float sbdh[Hsz], sdWdm[Fsz], sbdm[Fsz], sbtr[Fsz], sbfr[Fsz], sbwc[Fsz];
  __shared__ float sH[Hsz], sC[Hsz];
  __shared__ __align__(16) float sV[256];   // [cl_c(64); ml(64); h(128)] -> gates input
  __shared__ float sB2[128];                // [gamma_m(64); ml(64)] -> beta input
  __shared__ float sXl[Fsz], sMl[Fsz], sTl[Fsz];
  __shared__ float sXlhat[Fsz], sBeta[Fsz], sXlc[Fsz];
  __shared__ float sGates[NG];
  __shared__ float sRed[8];

  for (int i = tid; i < Hsz * Fsz; i += 512) sWdh[i >> 6][i & 63] = Wdh[i];
  for (int i = tid; i < Fsz * Hsz; i += 512) sWtr[i >> 7][i & 127] = Wtr[i];
  for (int i = tid; i < Fsz * Hsz; i += 512) sWwc[i >> 7][i & 127] = Wwc[i];
  for (int i = tid; i < Fsz * Fsz; i += 512) {
    int r = i >> 6, c = i & 63;
    sWfr[r][c] = (r == c) ? 0.f : Wfr[i];
  }
  if (tid < NG) sBias[tid] = bih[tid] + bhh[tid];
  if (tid < Hsz) { sbdh[tid] = bdh[tid]; sH[tid] = 0.f; sC[tid] = 0.f; }
  if (tid < Fsz) {
    sdWdm[tid] = Wdm[tid * Fsz + tid];
    sbdm[tid] = bdm[tid]; sbtr[tid] = btr[tid];
    sbfr[tid] = bfr[tid]; sbwc[tid] = bwc[tid];
  }
  __syncthreads();

  const float* xp = x + (size_t)b * Ssz * Fsz;
  const float* mp = m + (size_t)b * Ssz * Fsz;
  const float* tp = t + (size_t)b * Ssz * Fsz;
  float* op = out_imp + (size_t)b * Ssz * Fsz;

  float lacc = 0.f;

  for (int s = 0; s < Ssz; ++s) {
    const float idn = inv_denom[s];
    // P1: load x,m,t for this step
    if (tid < Fsz) {
      float xv = xp[s * Fsz + tid];
      float mv = mp[s * Fsz + tid];
      float tv = tp[s * Fsz + tid];
      sXl[tid] = xv; sMl[tid] = mv; sTl[tid] = tv;
      sV[64 + tid] = mv;
      sB2[64 + tid] = mv;
    }
    __syncthreads();

    // P2: gamma_h = exp(-relu(Wdh@t + bdh)); h *= gamma_h.  4 lanes/output.
    {
      int out = tid >> 2, p = tid & 3;
      float sum = 0.f;
#pragma unroll
      for (int i = 0; i < 16; ++i) {
        int k = p + 4 * i;
        sum += sWdh[out][k] * sTl[k];
      }
      sum += __shfl_xor(sum, 1);
      sum += __shfl_xor(sum, 2);
      if (p == 0) {
        float gh = __expf(-fmaxf(0.f, sum + sbdh[out]));
        float hv = sH[out] * gh;
        sH[out] = hv;
        sV[128 + out] = hv;
      }
      // gamma_m (elementwise) on threads 0..63
      if (tid < Fsz) {
        float gm = __expf(-fmaxf(0.f, sTl[tid] * sdWdm[tid] + sbdm[tid]));
        sB2[tid] = gm;
      }
    }
    __syncthreads();

    // P3: xl_hat = Wtr@h + btr (threads 0..255) || beta = Wwc@[gm;ml] + bwc (256..511)
    if (tid < 256) {
      int out = tid >> 2, p = tid & 3;
      float sum = 0.f;
#pragma unroll
      for (int i = 0; i < 32; ++i) {
        int k = p + 4 * i;
        sum += sWtr[out][k] * sH[k];
      }
      sum += __shfl_xor(sum, 1);
      sum += __shfl_xor(sum, 2);
      if (p == 0) {
        float xlh = sum + sbtr[out];
        sXlhat[out] = xlh;
        float xv = sXl[out], mv = sMl[out];
        sXlc[out] = mv * xv + (1.f - mv) * xlh;
        float d = xv - xlh;
        lacc += d * d * mv * idn;               // loss term 1
      }
    } else {
      int tt = tid - 256;
      int out = tt >> 2, p = tt & 3;
      float sum = 0.f;
#pragma unroll
      for (int i = 0; i < 32; ++i) {
        int k = p + 4 * i;
        sum += sWwc[out][k] * sB2[k];
      }
      sum += __shfl_xor(sum, 1);
      sum += __shfl_xor(sum, 2);
      if (p == 0) sBeta[out] = sum + sbwc[out];
    }
    __syncthreads();

    // P5: zl_hat = Wfr_m@xl_c + bfr; then cl_hat, cl_c, loss terms 2+3, output write.
    {
      int out = tid >> 3, p = tid & 7;
      float sum = 0.f;
#pragma unroll
      for (int i = 0; i < 8; ++i) {
        int k = p + 8 * i;
        sum += sWfr[out][k] * sXlc[k];
      }
      sum += __shfl_xor(sum, 1);
      sum += __shfl_xor(sum, 2);
      sum += __shfl_xor(sum, 4);
      if (p == 0) {
        float zl = sum + sbfr[out];
        float xv = sXl[out], mv = sMl[out];
        float xlh = sXlhat[out], beta = sBeta[out];
        float d2 = xv - zl;
        float clh = beta * zl + (1.f - beta) * xlh;
        float d3 = xv - clh;
        lacc += (d2 * d2 + d3 * d3) * mv * idn; // loss terms 2+3
        float clc = mv * xv + (1.f - mv) * clh;
        sV[out] = clc;
        op[s * Fsz + out] = clc;
      }
    }
    __syncthreads();

    // P7: gates[j] = bias[j] + sum_k Wcat_bf16[j][k] * v[k]   (k=0..255)
    {
      float acc = sBias[tid];
      const uint4* wp = ((const uint4*)Wpk) + tid;  // uint4 index kk*512 + j
      const float4* v4 = (const float4*)sV;
#pragma unroll 4
      for (int kk = 0; kk < 32; ++kk) {
        uint4 w = wp[kk * NG];
        float4 va = v4[kk * 2];
        float4 vb = v4[kk * 2 + 1];
        acc += __uint_as_float(w.x << 16)          * va.x;
        acc += __uint_as_float(w.x & 0xffff0000u)  * va.y;
        acc += __uint_as_float(w.y << 16)          * va.z;
        acc += __uint_as_float(w.y & 0xffff0000u)  * va.w;
        acc += __uint_as_float(w.z << 16)          * vb.x;
        acc += __uint_as_float(w.z & 0xffff0000u)  * vb.y;
        acc += __uint_as_float(w.w << 16)          * vb.z;
        acc += __uint_as_float(w.w & 0xffff0000u)  * vb.w;
      }
      sGates[tid] = acc;
    }
    __syncthreads();

    // P8: LSTM cell update
    if (tid < Hsz) {
      float gi = sGates[tid], gf = sGates[128 + tid], gg = sGates[256 + tid], go = sGates[384 + tid];
      float si = 1.f / (1.f + __expf(-gi));
      float sf = 1.f / (1.f + __expf(-gf));
      float so = 1.f / (1.f + __expf(-go));
      float c = sf * sC[tid] + si * tanhf(gg);
      sC[tid] = c;
      sH[tid] = so * tanhf(c);
    }
    __syncthreads();
  }

  // loss reduction: block -> atomic
  for (int off = 32; off > 0; off >>= 1) lacc += __shfl_xor(lacc, off);
  if ((tid & 63) == 0) sRed[tid >> 6] = lacc;
  __syncthreads();
  if (tid == 0) {
    float tot = 0.f;
#pragma unroll
    for (int w = 0; w < 8; ++w) tot += sRed[w];
    atomicAdd(out_loss, tot * (1.0f / Ssz));
  }
}

extern "C" void kernel_launch(void* const* d_in, const int* in_sizes, int n_in,
                              void* d_out, int out_size, void* d_ws, size_t ws_size,
                              hipStream_t stream) {
  const float* x   = (const float*)d_in[0];
  const float* m   = (const float*)d_in[1];
  const float* t   = (const float*)d_in[2];
  const float* Wdh = (const float*)d_in[3];
  const float* bdh = (const float*)d_in[4];
  const float* Wdm = (const float*)d_in[5];
  const float* bdm = (const float*)d_in[6];
  const float* Wtr = (const float*)d_in[7];
  const float* btr = (const float*)d_in[8];
  const float* Wfr = (const float*)d_in[9];
  const float* bfr = (const float*)d_in[10];
  const float* Wwc = (const float*)d_in[11];
  const float* bwc = (const float*)d_in[12];
  const float* Wih = (const float*)d_in[13];
  const float* Whh = (const float*)d_in[14];
  const float* bih = (const float*)d_in[15];
  const float* bhh = (const float*)d_in[16];

  float* inv_denom = (float*)d_ws;                       // 512 f32
  ushort_t* Wpk = (ushort_t*)((char*)d_ws + 2048);       // 256 KiB bf16 packed weights
  float* out_f = (float*)d_out;
  float* out_loss = out_f + (size_t)Bsz * Ssz * Fsz;

  denom_kernel<<<Ssz, 256, 0, stream>>>(m, inv_denom);
  pack_kernel<<<64, 256, 0, stream>>>(Wih, Whh, Wpk);
  hipMemsetAsync(out_loss, 0, sizeof(float), stream);
  rits_kernel<<<Bsz, 512, 0, stream>>>(x, m, t, Wdh, bdh, Wdm, bdm, Wtr, btr, Wfr, bfr,
                                       Wwc, bwc, bih, bhh, Wpk, inv_denom, out_f, out_loss);
}

// Round 2
// 1629.180 us; speedup vs baseline: 1.8365x; 1.8365x over previous
//
#include <hip/hip_runtime.h>
#include <hip/hip_bf16.h>

#define Bsz 256
#define Ssz 512
#define Fsz 64
#define Hsz 128
#define NG  512   // 4*H

typedef unsigned short ushort_t;
typedef __attribute__((ext_vector_type(8))) short short8v;
typedef __attribute__((ext_vector_type(4))) float float4v;

__device__ __forceinline__ ushort_t f2bf(float f) {
  unsigned int b = __float_as_uint(f);
  return (ushort_t)((b + 0x7fffu + ((b >> 16) & 1u)) >> 16);
}

// --- kernel 1: inv_denom[s] = 1 / (sum_{b,f} m[b,s,f] + 1e-5) ---
__global__ void denom_kernel(const float* __restrict__ m, float* __restrict__ inv_denom) {
  int s = blockIdx.x;
  int tid = threadIdx.x; // 256 threads, one per batch row
  const float4* mp = (const float4*)(m + ((size_t)tid * Ssz + s) * Fsz);
  float sum = 0.f;
#pragma unroll
  for (int i = 0; i < Fsz / 4; ++i) {
    float4 v = mp[i];
    sum += v.x + v.y + v.z + v.w;
  }
  for (int off = 32; off > 0; off >>= 1) sum += __shfl_xor(sum, off);
  __shared__ float red[4];
  if ((tid & 63) == 0) red[tid >> 6] = sum;
  __syncthreads();
  if (tid == 0) {
    float tot = red[0] + red[1] + red[2] + red[3];
    inv_denom[s] = 1.0f / (tot + 1e-5f);
  }
}

// --- kernel 2: pack [Wih | Whh] into bf16 MFMA B-fragments.
//     frag index g = (kt*32 + nt)*64 + lane ; element j:
//     B[k][n] with k = kt*32 + (lane>>4)*8 + j, n = lane&15, jout = nt*16+n. ---
__global__ void pack_kernel(const float* __restrict__ Wih, const float* __restrict__ Whh,
                            ushort_t* __restrict__ Wpk) {
  int g = blockIdx.x * blockDim.x + threadIdx.x;   // 0..16383
  if (g >= 16384) return;
  int lane = g & 63, nt = (g >> 6) & 31, kt = g >> 11;
  int jout = nt * 16 + (lane & 15);
  int kbase = kt * 32 + ((lane >> 4) << 3);
  ushort_t* dst = Wpk + (size_t)g * 8;
#pragma unroll
  for (int j = 0; j < 8; ++j) {
    int k = kbase + j;
    float w = (k < 128) ? Wih[jout * 128 + k] : Whh[jout * 128 + (k - 128)];
    dst[j] = f2bf(w);
  }
}

// --- kernel 3: the recurrence. One block per batch row, 512 threads. ---
__launch_bounds__(512, 2)
__global__ void rits_kernel(
    const float* __restrict__ x, const float* __restrict__ m, const float* __restrict__ t,
    const float* __restrict__ Wdh, const float* __restrict__ bdh,
    const float* __restrict__ Wdm, const float* __restrict__ bdm,
    const float* __restrict__ Wtr, const float* __restrict__ btr,
    const float* __restrict__ Wfr, const float* __restrict__ bfr,
    const float* __restrict__ Wwc, const float* __restrict__ bwc,
    const float* __restrict__ bih, const float* __restrict__ bhh,
    const ushort_t* __restrict__ Wpk, const float* __restrict__ inv_denom,
    float* __restrict__ out_imp, float* __restrict__ out_loss)
{
  const int b = blockIdx.x;
  const int tid = threadIdx.x;
  const int lane = tid & 63;
  const int wv = tid >> 6;

  __shared__ float sWdh[Hsz][68];    // [h][f]
  __shared__ float sWtr[Fsz][132];   // [f][h]
  __shared__ float sWwc[Fsz][132];   // [f][2f]
  __shared__ float sWfr[Fsz][68];    // [f][f], diag zeroed
  __shared__ float sbdh[Hsz], sdWdm[Fsz], sbdm[Fsz], sbtr[Fsz], sbfr[Fsz], sbwc[Fsz];
  __shared__ float sH[Hsz], sC[Hsz];
  __shared__ __align__(16) ushort_t sVh[256];  // bf16 V = [cl_c(64); ml(64); h(128)]
  __shared__ float sB2[128];                   // [gamma_m(64); ml(64)]
  __shared__ __align__(16) float sXl[Fsz], sMl[Fsz], sTl[Fsz];
  __shared__ float sXlhat[Fsz], sBeta[Fsz], sXlc[Fsz];
  __shared__ float sGates[NG];
  __shared__ float sRed[8];

  // stage small weights (f32, conflict-benign layouts)
  for (int i = tid; i < Hsz * Fsz; i += 512) sWdh[i >> 6][i & 63] = Wdh[i];
  for (int i = tid; i < Fsz * Hsz; i += 512) sWtr[i >> 7][i & 127] = Wtr[i];
  for (int i = tid; i < Fsz * Hsz; i += 512) sWwc[i >> 7][i & 127] = Wwc[i];
  for (int i = tid; i < Fsz * Fsz; i += 512) {
    int r = i >> 6, c = i & 63;
    sWfr[r][c] = (r == c) ? 0.f : Wfr[i];
  }
  if (tid < Hsz) { sbdh[tid] = bdh[tid]; sH[tid] = 0.f; sC[tid] = 0.f; }
  if (tid < Fsz) {
    sdWdm[tid] = Wdm[tid * Fsz + tid];
    sbdm[tid] = bdm[tid]; sbtr[tid] = btr[tid];
    sbfr[tid] = bfr[tid]; sbwc[tid] = bwc[tid];
  }

  // gates weights -> registers (B-fragments), bias -> registers
  const short8v* wp = (const short8v*)Wpk;
  short8v Bf[8][4];
#pragma unroll
  for (int kt = 0; kt < 8; ++kt)
#pragma unroll
    for (int n = 0; n < 4; ++n)
      Bf[kt][n] = wp[((kt * 32 + wv * 4 + n) << 6) + lane];
  float gb[4];
#pragma unroll
  for (int n = 0; n < 4; ++n) {
    int j = (wv * 4 + n) * 16 + (lane & 15);
    gb[n] = bih[j] + bhh[j];
  }

  const float* xp = x + (size_t)b * Ssz * Fsz;
  const float* mp = m + (size_t)b * Ssz * Fsz;
  const float* tp = t + (size_t)b * Ssz * Fsz;
  float* op = out_imp + (size_t)b * Ssz * Fsz;

  // prologue: load step-0 inputs
  float4 pre;
  if (tid < 16)      pre = *(const float4*)(xp + tid * 4);
  else if (tid < 32) pre = *(const float4*)(mp + (tid - 16) * 4);
  else if (tid < 48) pre = *(const float4*)(tp + (tid - 32) * 4);
  if (tid < 16) {
    *(float4*)&sXl[tid * 4] = pre;
  } else if (tid < 32) {
    int i = tid - 16;
    *(float4*)&sMl[i * 4] = pre;
    *(float4*)&sB2[64 + i * 4] = pre;
    sVh[64 + i * 4 + 0] = f2bf(pre.x);
    sVh[64 + i * 4 + 1] = f2bf(pre.y);
    sVh[64 + i * 4 + 2] = f2bf(pre.z);
    sVh[64 + i * 4 + 3] = f2bf(pre.w);
  } else if (tid < 48) {
    *(float4*)&sTl[(tid - 32) * 4] = pre;
  }
  __syncthreads();

  float lacc = 0.f;

  for (int s = 0; s < Ssz; ++s) {
    const float idn = inv_denom[s];

    // P2: gamma_h = exp(-relu(Wdh@t + bdh)); h *= gamma_h.  gamma_m elementwise.
    {
      int out = tid >> 2, p = tid & 3;
      float sum = 0.f;
#pragma unroll
      for (int i = 0; i < 16; ++i) {
        int k = p + 4 * i;
        sum += sWdh[out][k] * sTl[k];
      }
      sum += __shfl_xor(sum, 1);
      sum += __shfl_xor(sum, 2);
      if (p == 0) {
        float gh = __expf(-fmaxf(0.f, sum + sbdh[out]));
        float hv = sH[out] * gh;
        sH[out] = hv;
        sVh[128 + out] = f2bf(hv);
      }
      if (tid < Fsz) {
        float gm = __expf(-fmaxf(0.f, sTl[tid] * sdWdm[tid] + sbdm[tid]));
        sB2[tid] = gm;
      }
    }
    __syncthreads();

    // P3: xl_hat = Wtr@h + btr (tid<256) || beta = Wwc@[gm;ml] + bwc (tid>=256)
    if (tid < 256) {
      int out = tid >> 2, p = tid & 3;
      float sum = 0.f;
#pragma unroll
      for (int i = 0; i < 32; ++i) {
        int k = p + 4 * i;
        sum += sWtr[out][k] * sH[k];
      }
      sum += __shfl_xor(sum, 1);
      sum += __shfl_xor(sum, 2);
      if (p == 0) {
        float xlh = sum + sbtr[out];
        sXlhat[out] = xlh;
        float xv = sXl[out], mv = sMl[out];
        sXlc[out] = mv * xv + (1.f - mv) * xlh;
        float d = xv - xlh;
        lacc += d * d * mv * idn;               // loss term 1
      }
    } else {
      int tt = tid - 256;
      int out = tt >> 2, p = tt & 3;
      float sum = 0.f;
#pragma unroll
      for (int i = 0; i < 32; ++i) {
        int k = p + 4 * i;
        sum += sWwc[out][k] * sB2[k];
      }
      sum += __shfl_xor(sum, 1);
      sum += __shfl_xor(sum, 2);
      if (p == 0) sBeta[out] = sum + sbwc[out];
    }
    __syncthreads();

    // P5: zl_hat = Wfr_m@xl_c + bfr; cl_hat, cl_c, loss 2+3, output write.
    {
      int out = tid >> 3, p = tid & 7;
      float sum = 0.f;
#pragma unroll
      for (int i = 0; i < 8; ++i) {
        int k = p + 8 * i;
        sum += sWfr[out][k] * sXlc[k];
      }
      sum += __shfl_xor(sum, 1);
      sum += __shfl_xor(sum, 2);
      sum += __shfl_xor(sum, 4);
      if (p == 0) {
        float zl = sum + sbfr[out];
        float xv = sXl[out], mv = sMl[out];
        float xlh = sXlhat[out], beta = sBeta[out];
        float d2 = xv - zl;
        float clh = beta * zl + (1.f - beta) * xlh;
        float d3 = xv - clh;
        lacc += (d2 * d2 + d3 * d3) * mv * idn; // loss terms 2+3
        float clc = mv * xv + (1.f - mv) * clh;
        sVh[out] = f2bf(clc);
        op[s * Fsz + out] = clc;
      }
    }
    __syncthreads();

    // P7: gates via MFMA from register B-frags; prefetch next x/m/t.
    {
      int ps = (s + 1 < Ssz) ? s + 1 : Ssz - 1;
      if (tid < 16)      pre = *(const float4*)(xp + ps * Fsz + tid * 4);
      else if (tid < 32) pre = *(const float4*)(mp + ps * Fsz + (tid - 16) * 4);
      else if (tid < 48) pre = *(const float4*)(tp + ps * Fsz + (tid - 32) * 4);

      const char* abase = (const char*)sVh + ((lane >> 4) << 4);
      float4v acc[4];
#pragma unroll
      for (int n = 0; n < 4; ++n) acc[n] = (float4v){gb[n], gb[n], gb[n], gb[n]};
#pragma unroll
      for (int kt = 0; kt < 8; ++kt) {
        short8v a = *(const short8v*)(abase + kt * 64);
#pragma unroll
        for (int n = 0; n < 4; ++n)
          acc[n] = __builtin_amdgcn_mfma_f32_16x16x32_bf16(a, Bf[kt][n], acc[n], 0, 0, 0);
      }
      if (lane < 16) {
#pragma unroll
        for (int n = 0; n < 4; ++n)
          sGates[(wv * 4 + n) * 16 + lane] = acc[n][0];
      }
    }
    __syncthreads();

    // P8: LSTM cell update || write prefetched inputs for s+1
    if (tid < Hsz) {
      float gi = sGates[tid], gf = sGates[128 + tid], gg = sGates[256 + tid], go = sGates[384 + tid];
      float si = 1.f / (1.f + __expf(-gi));
      float sf = 1.f / (1.f + __expf(-gf));
      float so = 1.f / (1.f + __expf(-go));
      float c = sf * sC[tid] + si * tanhf(gg);
      sC[tid] = c;
      sH[tid] = so * tanhf(c);
    }
    if (tid < 16) {
      *(float4*)&sXl[tid * 4] = pre;
    } else if (tid < 32) {
      int i = tid - 16;
      *(float4*)&sMl[i * 4] = pre;
      *(float4*)&sB2[64 + i * 4] = pre;
      sVh[64 + i * 4 + 0] = f2bf(pre.x);
      sVh[64 + i * 4 + 1] = f2bf(pre.y);
      sVh[64 + i * 4 + 2] = f2bf(pre.z);
      sVh[64 + i * 4 + 3] = f2bf(pre.w);
    } else if (tid < 48) {
      *(float4*)&sTl[(tid - 32) * 4] = pre;
    }
    __syncthreads();
  }

  // loss reduction: block -> atomic
  for (int off = 32; off > 0; off >>= 1) lacc += __shfl_xor(lacc, off);
  if ((tid & 63) == 0) sRed[tid >> 6] = lacc;
  __syncthreads();
  if (tid == 0) {
    float tot = 0.f;
#pragma unroll
    for (int w = 0; w < 8; ++w) tot += sRed[w];
    atomicAdd(out_loss, tot * (1.0f / Ssz));
  }
}

extern "C" void kernel_launch(void* const* d_in, const int* in_sizes, int n_in,
                              void* d_out, int out_size, void* d_ws, size_t ws_size,
                              hipStream_t stream) {
  const float* x   = (const float*)d_in[0];
  const float* m   = (const float*)d_in[1];
  const float* t   = (const float*)d_in[2];
  const float* Wdh = (const float*)d_in[3];
  const float* bdh = (const float*)d_in[4];
  const float* Wdm = (const float*)d_in[5];
  const float* bdm = (const float*)d_in[6];
  const float* Wtr = (const float*)d_in[7];
  const float* btr = (const float*)d_in[8];
  const float* Wfr = (const float*)d_in[9];
  const float* bfr = (const float*)d_in[10];
  const float* Wwc = (const float*)d_in[11];
  const float* bwc = (const float*)d_in[12];
  const float* Wih = (const float*)d_in[13];
  const float* Whh = (const float*)d_in[14];
  const float* bih = (const float*)d_in[15];
  const float* bhh = (const float*)d_in[16];

  float* inv_denom = (float*)d_ws;                       // 512 f32
  ushort_t* Wpk = (ushort_t*)((char*)d_ws + 2048);       // 256 KiB bf16 MFMA frags
  float* out_f = (float*)d_out;
  float* out_loss = out_f + (size_t)Bsz * Ssz * Fsz;

  denom_kernel<<<Ssz, 256, 0, stream>>>(m, inv_denom);
  pack_kernel<<<64, 256, 0, stream>>>(Wih, Whh, Wpk);
  hipMemsetAsync(out_loss, 0, sizeof(float), stream);
  rits_kernel<<<Bsz, 512, 0, stream>>>(x, m, t, Wdh, bdh, Wdm, bdm, Wtr, btr, Wfr, bfr,
                                       Wwc, bwc, bih, bhh, Wpk, inv_denom, out_f, out_loss);
}

// Round 3
// 1485.668 us; speedup vs baseline: 2.0139x; 1.0966x over previous
//
#include <hip/hip_runtime.h>
#include <hip/hip_bf16.h>

#define Bsz 256
#define Ssz 512
#define Fsz 64
#define Hsz 128
#define NG  512   // 4*H

typedef unsigned short ushort_t;
typedef __attribute__((ext_vector_type(8))) short short8v;
typedef __attribute__((ext_vector_type(4))) float float4v;

__device__ __forceinline__ ushort_t f2bf(float f) {
  unsigned int b = __float_as_uint(f);
  return (ushort_t)((b + 0x7fffu + ((b >> 16) & 1u)) >> 16);
}
__device__ __forceinline__ float bf2f(ushort_t u) {
  return __uint_as_float(((unsigned int)u) << 16);
}
__device__ __forceinline__ float sigf(float v) { return 1.f / (1.f + __expf(-v)); }
__device__ __forceinline__ float tanhf_fast(float v) {
  float e = __expf(2.f * v);
  return 1.f - 2.f / (e + 1.f);
}

// --- kernel 1: inv_denom[s] = 1 / (sum_{b,f} m[b,s,f] + 1e-5) ---
__global__ void denom_kernel(const float* __restrict__ m, float* __restrict__ inv_denom) {
  int s = blockIdx.x;
  int tid = threadIdx.x; // 256 threads, one per batch row
  const float4* mp = (const float4*)(m + ((size_t)tid * Ssz + s) * Fsz);
  float sum = 0.f;
#pragma unroll
  for (int i = 0; i < Fsz / 4; ++i) {
    float4 v = mp[i];
    sum += v.x + v.y + v.z + v.w;
  }
  for (int off = 32; off > 0; off >>= 1) sum += __shfl_xor(sum, off);
  __shared__ float red[4];
  if ((tid & 63) == 0) red[tid >> 6] = sum;
  __syncthreads();
  if (tid == 0) {
    float tot = red[0] + red[1] + red[2] + red[3];
    inv_denom[s] = 1.0f / (tot + 1e-5f);
  }
}

// --- kernel 2: pack [Wih | Whh] into bf16 MFMA B-fragments (validated r2) ---
__global__ void pack_kernel(const float* __restrict__ Wih, const float* __restrict__ Whh,
                            ushort_t* __restrict__ Wpk) {
  int g = blockIdx.x * blockDim.x + threadIdx.x;   // 0..16383
  if (g >= 16384) return;
  int lane = g & 63, nt = (g >> 6) & 31, kt = g >> 11;
  int jout = nt * 16 + (lane & 15);
  int kbase = kt * 32 + ((lane >> 4) << 3);
  ushort_t* dst = Wpk + (size_t)g * 8;
#pragma unroll
  for (int j = 0; j < 8; ++j) {
    int k = kbase + j;
    float w = (k < 128) ? Wih[jout * 128 + k] : Whh[jout * 128 + (k - 128)];
    dst[j] = f2bf(w);
  }
}

// --- kernel 3: gamma_h precompute: gh[row][128] = exp(-relu(t[row,:]@WdhT + bdh)), bf16 out.
//     64 rows/block, 256 threads (4 waves x 16 rows). ---
__global__ void gh_kernel(const float* __restrict__ t, const float* __restrict__ Wdh,
                          const float* __restrict__ bdh, ushort_t* __restrict__ gh) {
  const int tid = threadIdx.x;
  const int lane = tid & 63, wv = tid >> 6;
  const int row0 = blockIdx.x * 64;
  __shared__ __align__(16) ushort_t st[64][72];    // t tile bf16 (pad 72)
  __shared__ __align__(16) ushort_t sO[64][136];   // output staging
  __shared__ float sbdh[128];
  if (tid < 128) sbdh[tid] = bdh[tid];
  // B-frags: B[k][n] = Wdh[n][k]; 2 kt x 8 nt, same for all waves
  short8v Bf[2][8];
#pragma unroll
  for (int kt = 0; kt < 2; ++kt)
#pragma unroll
    for (int nt = 0; nt < 8; ++nt) {
      int col = nt * 16 + (lane & 15);
      int k0 = kt * 32 + ((lane >> 4) << 3);
      float4 wa = *(const float4*)(Wdh + col * 64 + k0);
      float4 wb = *(const float4*)(Wdh + col * 64 + k0 + 4);
      short8v bb;
      bb[0] = (short)f2bf(wa.x); bb[1] = (short)f2bf(wa.y);
      bb[2] = (short)f2bf(wa.z); bb[3] = (short)f2bf(wa.w);
      bb[4] = (short)f2bf(wb.x); bb[5] = (short)f2bf(wb.y);
      bb[6] = (short)f2bf(wb.z); bb[7] = (short)f2bf(wb.w);
      Bf[kt][nt] = bb;
    }
  // stage t tile (64x64 f32 -> bf16)
  const float* tb = t + (size_t)row0 * 64;
  {
    int r = tid >> 2, c0 = (tid & 3) * 16;
#pragma unroll
    for (int q = 0; q < 4; ++q) {
      float4 v = *(const float4*)(tb + r * 64 + c0 + q * 4);
      st[r][c0 + q * 4 + 0] = f2bf(v.x);
      st[r][c0 + q * 4 + 1] = f2bf(v.y);
      st[r][c0 + q * 4 + 2] = f2bf(v.z);
      st[r][c0 + q * 4 + 3] = f2bf(v.w);
    }
  }
  __syncthreads();
  float4v acc[8] = {};
#pragma unroll
  for (int kt = 0; kt < 2; ++kt) {
    int r = wv * 16 + (lane & 15);
    int k0 = kt * 32 + ((lane >> 4) << 3);
    short8v a = *(const short8v*)&st[r][k0];
#pragma unroll
    for (int nt = 0; nt < 8; ++nt)
      acc[nt] = __builtin_amdgcn_mfma_f32_16x16x32_bf16(a, Bf[kt][nt], acc[nt], 0, 0, 0);
  }
#pragma unroll
  for (int nt = 0; nt < 8; ++nt)
#pragma unroll
    for (int rr = 0; rr < 4; ++rr) {
      int col = nt * 16 + (lane & 15);
      int row = wv * 16 + ((lane >> 4) << 2) + rr;
      float v = acc[nt][rr] + sbdh[col];
      sO[row][col] = f2bf(__expf(-fmaxf(0.f, v)));
    }
  __syncthreads();
  {
    int r = tid >> 2, c0 = (tid & 3) * 32;
    const uint4* src = (const uint4*)&sO[r][c0];
    uint4* dst = (uint4*)(gh + (size_t)(row0 + r) * 128 + c0);
#pragma unroll
    for (int q = 0; q < 4; ++q) dst[q] = src[q];
  }
}

// --- kernel 4: beta precompute: beta[row][64] = [gm; m] @ WwcT + bwc, bf16 out. ---
__global__ void beta_kernel(const float* __restrict__ t, const float* __restrict__ m,
                            const float* __restrict__ Wdm, const float* __restrict__ bdm,
                            const float* __restrict__ Wwc, const float* __restrict__ bwc,
                            ushort_t* __restrict__ beta) {
  const int tid = threadIdx.x;
  const int lane = tid & 63, wv = tid >> 6;
  const int row0 = blockIdx.x * 64;
  __shared__ __align__(16) ushort_t sA[64][136];   // [gm(64); m(64)] bf16
  __shared__ __align__(16) ushort_t sO[64][72];
  __shared__ float sdw[64], sbd[64], sbwc[64];
  if (tid < 64) {
    sdw[tid] = Wdm[tid * 64 + tid];
    sbd[tid] = bdm[tid];
    sbwc[tid] = bwc[tid];
  }
  // B-frags: B[k][n] = Wwc[n][k]; 4 kt x 4 nt
  short8v Bf[4][4];
#pragma unroll
  for (int kt = 0; kt < 4; ++kt)
#pragma unroll
    for (int nt = 0; nt < 4; ++nt) {
      int col = nt * 16 + (lane & 15);
      int k0 = kt * 32 + ((lane >> 4) << 3);
      float4 wa = *(const float4*)(Wwc + col * 128 + k0);
      float4 wb = *(const float4*)(Wwc + col * 128 + k0 + 4);
      short8v bb;
      bb[0] = (short)f2bf(wa.x); bb[1] = (short)f2bf(wa.y);
      bb[2] = (short)f2bf(wa.z); bb[3] = (short)f2bf(wa.w);
      bb[4] = (short)f2bf(wb.x); bb[5] = (short)f2bf(wb.y);
      bb[6] = (short)f2bf(wb.z); bb[7] = (short)f2bf(wb.w);
      Bf[kt][nt] = bb;
    }
  __syncthreads();   // sdw/sbd ready
  {
    int r = tid >> 2, c0 = (tid & 3) * 16;
    const float* tb = t + (size_t)row0 * 64;
    const float* mb = m + (size_t)row0 * 64;
#pragma unroll
    for (int q = 0; q < 4; ++q) {
      float4 tv = *(const float4*)(tb + r * 64 + c0 + q * 4);
      float4 mv = *(const float4*)(mb + r * 64 + c0 + q * 4);
      int c = c0 + q * 4;
      sA[r][c + 0] = f2bf(__expf(-fmaxf(0.f, tv.x * sdw[c + 0] + sbd[c + 0])));
      sA[r][c + 1] = f2bf(__expf(-fmaxf(0.f, tv.y * sdw[c + 1] + sbd[c + 1])));
      sA[r][c + 2] = f2bf(__expf(-fmaxf(0.f, tv.z * sdw[c + 2] + sbd[c + 2])));
      sA[r][c + 3] = f2bf(__expf(-fmaxf(0.f, tv.w * sdw[c + 3] + sbd[c + 3])));
      sA[r][64 + c + 0] = f2bf(mv.x);
      sA[r][64 + c + 1] = f2bf(mv.y);
      sA[r][64 + c + 2] = f2bf(mv.z);
      sA[r][64 + c + 3] = f2bf(mv.w);
    }
  }
  __syncthreads();
  float4v acc[4] = {};
#pragma unroll
  for (int kt = 0; kt < 4; ++kt) {
    int r = wv * 16 + (lane & 15);
    int k0 = kt * 32 + ((lane >> 4) << 3);
    short8v a = *(const short8v*)&sA[r][k0];
#pragma unroll
    for (int nt = 0; nt < 4; ++nt)
      acc[nt] = __builtin_amdgcn_mfma_f32_16x16x32_bf16(a, Bf[kt][nt], acc[nt], 0, 0, 0);
  }
#pragma unroll
  for (int nt = 0; nt < 4; ++nt)
#pragma unroll
    for (int rr = 0; rr < 4; ++rr) {
      int col = nt * 16 + (lane & 15);
      int row = wv * 16 + ((lane >> 4) << 2) + rr;
      sO[row][col] = f2bf(acc[nt][rr] + sbwc[col]);
    }
  __syncthreads();
  {
    int r = tid >> 2, c0 = (tid & 3) * 16;
    const uint4* src = (const uint4*)&sO[r][c0];
    uint4* dst = (uint4*)(beta + (size_t)(row0 + r) * 64 + c0);
    dst[0] = src[0];
    dst[1] = src[1];
  }
}

// --- kernel 5: the recurrence. One block per batch row, 512 threads, 4 barriers/step. ---
__launch_bounds__(512, 1)
__global__ void rits_kernel(
    const float* __restrict__ x, const float* __restrict__ m,
    const float* __restrict__ Wtr, const float* __restrict__ btr,
    const float* __restrict__ Wfr, const float* __restrict__ bfr,
    const float* __restrict__ bih, const float* __restrict__ bhh,
    const ushort_t* __restrict__ Wpk, const float* __restrict__ inv_denom,
    const ushort_t* __restrict__ ghp, const ushort_t* __restrict__ betap,
    float* __restrict__ out_imp, float* __restrict__ out_loss)
{
  const int b = blockIdx.x;
  const int tid = threadIdx.x;
  const int lane = tid & 63;
  const int wv = tid >> 6;

  __shared__ float sIdn[Ssz];
  __shared__ float sPart[8][64];
  __shared__ float sPartF[8][64];
  __shared__ float sGates[NG];
  __shared__ float sH[Hsz];
  __shared__ __align__(16) ushort_t sVh[256];  // V = [cl_c(64); ml(64); h(128)] bf16

  sIdn[tid] = inv_denom[tid];

  // register-resident small weights (partial-split over waves)
  float wtr_r[16];
  {
    const float* wb = Wtr + lane * 128 + wv * 16;
#pragma unroll
    for (int q = 0; q < 4; ++q) {
      float4 v = *(const float4*)(wb + q * 4);
      wtr_r[q * 4 + 0] = v.x; wtr_r[q * 4 + 1] = v.y;
      wtr_r[q * 4 + 2] = v.z; wtr_r[q * 4 + 3] = v.w;
    }
  }
  float wfr_r[8];
  {
    const float* wb = Wfr + lane * 64 + wv * 8;
#pragma unroll
    for (int q = 0; q < 2; ++q) {
      float4 v = *(const float4*)(wb + q * 4);
      wfr_r[q * 4 + 0] = v.x; wfr_r[q * 4 + 1] = v.y;
      wfr_r[q * 4 + 2] = v.z; wfr_r[q * 4 + 3] = v.w;
    }
#pragma unroll
    for (int i = 0; i < 8; ++i)
      if (lane == wv * 8 + i) wfr_r[i] = 0.f;   // zero diagonal
  }
  const float btr_r = btr[lane];
  const float bfr_r = bfr[lane];

  // gates weights -> registers (B-fragments), bias -> registers
  const short8v* wp = (const short8v*)Wpk;
  short8v Bf[8][4];
#pragma unroll
  for (int kt = 0; kt < 8; ++kt)
#pragma unroll
    for (int n = 0; n < 4; ++n)
      Bf[kt][n] = wp[((kt * 32 + wv * 4 + n) << 6) + lane];
  float gb[4];
#pragma unroll
  for (int n = 0; n < 4; ++n) {
    int j = (wv * 4 + n) * 16 + (lane & 15);
    gb[n] = bih[j] + bhh[j];
  }

  const float* xp = x + (size_t)b * Ssz * Fsz;
  const float* mp = m + (size_t)b * Ssz * Fsz;
  const ushort_t* ghb = ghp + (size_t)b * Ssz * 128;
  const ushort_t* beb = betap + (size_t)b * Ssz * 64;
  float* op = out_imp + (size_t)b * Ssz * Fsz;

  if (tid < Hsz) sH[tid] = 0.f;
  if (tid < 128) sVh[128 + tid] = 0;
  float c_reg = 0.f;

  // step-0 inputs (per-lane registers, redundant across waves -> L2 broadcast)
  float xv_cur = xp[lane];
  float mv_cur = mp[lane];
  float bet_cur = bf2f(beb[lane]);
  if (wv == 0) sVh[64 + lane] = f2bf(mv_cur);
  __syncthreads();

  float lacc = 0.f;

  for (int s = 0; s < Ssz; ++s) {
    // ================= Phase B =================
    // prefetch next-step inputs into registers
    const int ps = (s + 1 < Ssz) ? s + 1 : Ssz - 1;
    float xv_nxt = xp[ps * 64 + lane];
    float mv_nxt = mp[ps * 64 + lane];
    ushort_t bet_raw = beb[ps * 64 + lane];
    ushort_t gh_raw = 0;
    if (tid < 128) gh_raw = ghb[(size_t)ps * 128 + tid];

    // Wtr partial: out = lane, k-chunk = wv*16..+16 (h broadcast-read from LDS)
    {
      const float4* h4 = (const float4*)&sH[wv * 16];
      float4 h0 = h4[0], h1 = h4[1], h2 = h4[2], h3 = h4[3];
      float part = wtr_r[0] * h0.x + wtr_r[1] * h0.y + wtr_r[2] * h0.z + wtr_r[3] * h0.w
                 + wtr_r[4] * h1.x + wtr_r[5] * h1.y + wtr_r[6] * h1.z + wtr_r[7] * h1.w
                 + wtr_r[8] * h2.x + wtr_r[9] * h2.y + wtr_r[10] * h2.z + wtr_r[11] * h2.w
                 + wtr_r[12] * h3.x + wtr_r[13] * h3.y + wtr_r[14] * h3.z + wtr_r[15] * h3.w;
      sPart[wv][lane] = part;
    }

    // gates partial: kt 2..7 (ml, h parts of V)
    float4v acc[4];
#pragma unroll
    for (int n = 0; n < 4; ++n) acc[n] = (float4v){gb[n], gb[n], gb[n], gb[n]};
    {
      const char* abase = (const char*)sVh + ((lane >> 4) << 4);
#pragma unroll
      for (int kt = 2; kt < 8; ++kt) {
        short8v a = *(const short8v*)(abase + kt * 64);
#pragma unroll
        for (int n = 0; n < 4; ++n)
          acc[n] = __builtin_amdgcn_mfma_f32_16x16x32_bf16(a, Bf[kt][n], acc[n], 0, 0, 0);
      }
    }
    __syncthreads();

    // ================= Phase C' ================
    float xlh = btr_r;
#pragma unroll
    for (int w = 0; w < 8; ++w) xlh += sPart[w][lane];
    const float xv = xv_cur, mv = mv_cur;
    const float xlc = mv * xv + (1.f - mv) * xlh;
    const float idn = sIdn[s];
    if (wv == 0) { float d = xv - xlh; lacc += d * d * mv * idn; }
    {
      float pf = 0.f;
#pragma unroll
      for (int i = 0; i < 8; ++i) pf += wfr_r[i] * __shfl(xlc, wv * 8 + i);
      sPartF[wv][lane] = pf;
    }
    __syncthreads();

    // ================= Phase E' ================
    float zl = bfr_r;
#pragma unroll
    for (int w = 0; w < 8; ++w) zl += sPartF[w][lane];
    const float beta = bet_cur;
    const float clh = beta * zl + (1.f - beta) * xlh;
    const float clc = mv * xv + (1.f - mv) * clh;
    if (wv == 0) {
      float d2 = xv - zl, d3 = xv - clh;
      lacc += (d2 * d2 + d3 * d3) * mv * idn;
      op[s * 64 + lane] = clc;
    }
    {
      const int kb = (lane >> 4) << 3;
      short8v A0, A1;
#pragma unroll
      for (int j = 0; j < 8; ++j) {
        A0[j] = (short)f2bf(__shfl(clc, kb + j));
        A1[j] = (short)f2bf(__shfl(clc, 32 + kb + j));
      }
#pragma unroll
      for (int n = 0; n < 4; ++n) {
        acc[n] = __builtin_amdgcn_mfma_f32_16x16x32_bf16(A0, Bf[0][n], acc[n], 0, 0, 0);
        acc[n] = __builtin_amdgcn_mfma_f32_16x16x32_bf16(A1, Bf[1][n], acc[n], 0, 0, 0);
      }
      if (lane < 16) {
#pragma unroll
        for (int n = 0; n < 4; ++n)
          sGates[(wv * 4 + n) * 16 + lane] = acc[n][0];
      }
    }
    __syncthreads();

    // ================= Phase G =================
    if (tid < 128) {
      float gi = sGates[tid], gf = sGates[128 + tid];
      float gg = sGates[256 + tid], go = sGates[384 + tid];
      float cc = sigf(gf) * c_reg + sigf(gi) * tanhf_fast(gg);
      c_reg = cc;
      float hn = sigf(go) * tanhf_fast(cc);
      float hv = hn * bf2f(gh_raw);     // pre-scale with gamma_h(s+1)
      sH[tid] = hv;
      sVh[128 + tid] = f2bf(hv);
    }
    if (wv == 0) sVh[64 + lane] = f2bf(mv_nxt);   // ml for s+1
    __syncthreads();

    xv_cur = xv_nxt;
    mv_cur = mv_nxt;
    bet_cur = bf2f(bet_raw);
  }

  // loss: only wave 0 accumulated
  if (wv == 0) {
    for (int off = 32; off > 0; off >>= 1) lacc += __shfl_xor(lacc, off);
    if (lane == 0) atomicAdd(out_loss, lacc * (1.0f / Ssz));
  }
}

extern "C" void kernel_launch(void* const* d_in, const int* in_sizes, int n_in,
                              void* d_out, int out_size, void* d_ws, size_t ws_size,
                              hipStream_t stream) {
  const float* x   = (const float*)d_in[0];
  const float* m   = (const float*)d_in[1];
  const float* t   = (const float*)d_in[2];
  const float* Wdh = (const float*)d_in[3];
  const float* bdh = (const float*)d_in[4];
  const float* Wdm = (const float*)d_in[5];
  const float* bdm = (const float*)d_in[6];
  const float* Wtr = (const float*)d_in[7];
  const float* btr = (const float*)d_in[8];
  const float* Wfr = (const float*)d_in[9];
  const float* bfr = (const float*)d_in[10];
  const float* Wwc = (const float*)d_in[11];
  const float* bwc = (const float*)d_in[12];
  const float* Wih = (const float*)d_in[13];
  const float* Whh = (const float*)d_in[14];
  const float* bih = (const float*)d_in[15];
  const float* bhh = (const float*)d_in[16];

  char* ws = (char*)d_ws;
  float* inv_denom = (float*)ws;                       // 2 KiB
  ushort_t* Wpk    = (ushort_t*)(ws + 2048);           // 256 KiB
  ushort_t* gh_ws  = (ushort_t*)(ws + 264192);         // 32 MiB  (B*S*128 bf16)
  ushort_t* be_ws  = (ushort_t*)(ws + 264192 + (size_t)Bsz * Ssz * 128 * 2);  // 16 MiB
  float* out_f = (float*)d_out;
  float* out_loss = out_f + (size_t)Bsz * Ssz * Fsz;

  denom_kernel<<<Ssz, 256, 0, stream>>>(m, inv_denom);
  pack_kernel<<<64, 256, 0, stream>>>(Wih, Whh, Wpk);
  gh_kernel<<<(Bsz * Ssz) / 64, 256, 0, stream>>>(t, Wdh, bdh, gh_ws);
  beta_kernel<<<(Bsz * Ssz) / 64, 256, 0, stream>>>(t, m, Wdm, bdm, Wwc, bwc, be_ws);
  hipMemsetAsync(out_loss, 0, sizeof(float), stream);
  rits_kernel<<<Bsz, 512, 0, stream>>>(x, m, Wtr, btr, Wfr, bfr, bih, bhh,
                                       Wpk, inv_denom, gh_ws, be_ws, out_f, out_loss);
}